// Round 6
// baseline (137.813 us; speedup 1.0000x reference)
//
#include <hip/hip_runtime.h>
#include <math.h>

// HW exp2 (v_exp_f32, quarter-rate trans pipe: ~16 cy/wave64 — confirmed by
// R3/R4 A/B) when available.
#if defined(__has_builtin)
#  if __has_builtin(__builtin_amdgcn_exp2f)
#    define EXP2F(x) __builtin_amdgcn_exp2f(x)
#  endif
#endif
#ifndef EXP2F
#  define EXP2F(x) __expf(0.69314718055994530942f * (x))
#endif

typedef float v2f __attribute__((ext_vector_type(2)));
typedef int   v2i __attribute__((ext_vector_type(2)));

// Inline functions (NOT macros — braced v2f literals contain commas and
// blow up function-like macro argument parsing; that was R5's compile fail).
__device__ __forceinline__ v2f v2fma(v2f a, v2f b, v2f c) {
#if defined(__has_builtin) && __has_builtin(__builtin_elementwise_fma)
  return __builtin_elementwise_fma(a, b, c);
#else
  v2f r; r.x = fmaf(a.x, b.x, c.x); r.y = fmaf(a.y, b.y, c.y); return r;
#endif
}
__device__ __forceinline__ v2f v2max(v2f a, v2f b) {
#if defined(__has_builtin) && __has_builtin(__builtin_elementwise_max)
  return __builtin_elementwise_max(a, b);
#else
  v2f r; r.x = fmaxf(a.x, b.x); r.y = fmaxf(a.y, b.y); return r;
#endif
}
__device__ __forceinline__ v2f v2min(v2f a, v2f b) {
#if defined(__has_builtin) && __has_builtin(__builtin_elementwise_min)
  return __builtin_elementwise_min(a, b);
#else
  v2f r; r.x = fminf(a.x, b.x); r.y = fminf(a.y, b.y); return r;
#endif
}

// Packed full-rate exp2: RNE via magic constant, deg-3 Taylor on [-0.5,0.5]
// (rel err <= 6e-4), exponent rebuilt integer-side. ~6 pk + 2 int ops for
// TWO elements (~4-5 full-rate instrs/z vs 16-cy trans). Valid |x| < 512.
__device__ __forceinline__ v2f fast_exp2_v2(v2f x) {
  const v2f M  = {12582912.0f, 12582912.0f};  // 1.5 * 2^23
  const v2f C2 = {0.055504109f, 0.055504109f};
  const v2f C1 = {0.24022651f, 0.24022651f};
  const v2f C0 = {0.69314718f, 0.69314718f};
  const v2f ONE = {1.0f, 1.0f};
  v2f y = x + M;
  v2f n = y - M;
  v2f f = x - n;
  v2f p = v2fma(f, C2, C1);
  p = v2fma(f, p, C0);
  p = v2fma(f, p, ONE);
  v2i yi = __builtin_bit_cast(v2i, y);
  v2i pi = __builtin_bit_cast(v2i, p);
  v2i r  = (yi << 23) + pi;
  return __builtin_bit_cast(v2f, r);
}

// One layer of the OR-gate net:
//   aw = leaky_clamp(W, 0, 1, 0.1); z = h*aw
//   out[b,o] = sum_i z * softmax_i(tau*z); hout = 1 - out
// Folding: arg = c2*z, c2 = tau*log2(e); sum z*e = (sum arg*e)/c2.
//
// R4 evidence: R3 (all-trans) == R4 (half fast-scalar) to 0.04% -> both pipes
// ~balanced at ~16 cy / 64 z; v_exp_f32 is quarter-rate. This round: packed
// fp32 (v_pk_*) for all full-rate math, BB=8 to amortize the W-clamp, hybrid
// split pair0->trans pipe / pair1->packed fast_exp2 (r=0.5 ~ optimum).
template <int IN, int OUT, int BB, bool FIRST>
__launch_bounds__(256)
__global__ void or_layer(const float* __restrict__ hin,
                         const float* __restrict__ W,
                         const float* __restrict__ tau_ptr,
                         float* __restrict__ hout,
                         float tau_floor) {
  constexpr int OBB = 2;                 // outputs per 16-lane group
  constexpr int NIT = IN / 64;           // 16 lanes x float4 per iter
  constexpr int nOT = OUT / 32;          // 4 waves x 8 outputs per block

  const int lane = threadIdx.x & 63;
  const int wid  = threadIdx.x >> 6;
  const int il   = lane & 15;            // i-lane within group
  const int og   = lane >> 4;            // o-group 0..3

  const int ot = blockIdx.x % nOT;
  const int bt = blockIdx.x / nOT;
  const int b0 = bt * BB;
  const int o0 = ot * 32 + wid * 8 + og * OBB;

  const float ta  = tau_ptr[0];
  const float tau = tau_floor + (ta >= 0.0f ? ta : 0.05f * ta);
  const float c2  = tau * 1.44269504088896340736f;  // tau * log2(e)
  const v2f   c2v = {c2, c2};
  const v2f   ZERO = {0.0f, 0.0f};
  const v2f   ONE  = {1.0f, 1.0f};
  const v2f   SLOPE = {0.1f, 0.1f};

  const float4* __restrict__ Wv = (const float4*)W;
  const float4* __restrict__ Hv = (const float4*)hin;

  v2f s[BB][OBB], t[BB][OBB];            // packed accumulators (pair lanes)
#pragma unroll
  for (int r = 0; r < BB; ++r)
#pragma unroll
    for (int c = 0; c < OBB; ++c) {
      s[r][c] = ZERO;
      t[r][c] = ZERO;
    }

#pragma unroll 1
  for (int ic = 0; ic < NIT; ++ic) {
    const int i4 = ic * 16 + il;         // float4 index within [0, IN/4)

    v2f hp[BB][2];
    if (FIRST) {
      // hin is x: (128, IN/2); h = concat(x, 1-x). 64-float chunks align
      // with the IN/2 boundary -> branch uniform per iteration.
      constexpr int HALF4 = IN / 8;
      if (i4 < HALF4) {
#pragma unroll
        for (int r = 0; r < BB; ++r) {
          float4 v = Hv[(b0 + r) * HALF4 + i4];
          v2f a; a.x = v.x; a.y = v.y;
          v2f b; b.x = v.z; b.y = v.w;
          hp[r][0] = a; hp[r][1] = b;
        }
      } else {
#pragma unroll
        for (int r = 0; r < BB; ++r) {
          float4 v = Hv[(b0 + r) * HALF4 + (i4 - HALF4)];
          v2f a; a.x = v.x; a.y = v.y;
          v2f b; b.x = v.z; b.y = v.w;
          hp[r][0] = ONE - a; hp[r][1] = ONE - b;
        }
      }
    } else {
#pragma unroll
      for (int r = 0; r < BB; ++r) {
        float4 v = Hv[(b0 + r) * (IN / 4) + i4];
        v2f a; a.x = v.x; a.y = v.y;
        v2f b; b.x = v.z; b.y = v.w;
        hp[r][0] = a; hp[r][1] = b;
      }
    }

    // cw = c2 * leaky_clamp(W) on packed pairs, amortized over BB rows.
    v2f cw[OBB][2];
#pragma unroll
    for (int c = 0; c < OBB; ++c) {
      float4 v = Wv[(o0 + c) * (IN / 4) + i4];
      v2f wp0; wp0.x = v.x; wp0.y = v.y;
      v2f wp1; wp1.x = v.z; wp1.y = v.w;
      v2f wp[2] = {wp0, wp1};
#pragma unroll
      for (int q = 0; q < 2; ++q) {
        v2f m  = v2min(v2max(wp[q], ZERO), ONE);
        v2f aw = v2fma(wp[q] - m, SLOPE, m);
        cw[c][q] = aw * c2v;
      }
    }

#pragma unroll
    for (int r = 0; r < BB; ++r)
#pragma unroll
      for (int c = 0; c < OBB; ++c) {
        // pair 0 -> trans pipe (2x v_exp_f32)
        {
          v2f arg = cw[c][0] * hp[r][0];
          v2f e;
          e.x = EXP2F(arg.x);
          e.y = EXP2F(arg.y);
          s[r][c] += e;
          t[r][c]  = v2fma(arg, e, t[r][c]);
        }
        // pair 1 -> full-rate packed fast path
        {
          v2f arg = cw[c][1] * hp[r][1];
          v2f e   = fast_exp2_v2(arg);
          s[r][c] += e;
          t[r][c]  = v2fma(arg, e, t[r][c]);
        }
      }
  }

  // Fold packed halves, then reduce across the 16 i-lanes of each group.
  float ss[BB][OBB], tt[BB][OBB];
#pragma unroll
  for (int r = 0; r < BB; ++r)
#pragma unroll
    for (int c = 0; c < OBB; ++c) {
      ss[r][c] = s[r][c].x + s[r][c].y;
      tt[r][c] = t[r][c].x + t[r][c].y;
    }
#pragma unroll
  for (int m = 1; m < 16; m <<= 1) {
#pragma unroll
    for (int r = 0; r < BB; ++r)
#pragma unroll
      for (int c = 0; c < OBB; ++c) {
        ss[r][c] += __shfl_xor(ss[r][c], m, 64);
        tt[r][c] += __shfl_xor(tt[r][c], m, 64);
      }
  }

  if (il == 0) {
    const float inv_c2 = 1.0f / c2;
#pragma unroll
    for (int r = 0; r < BB; ++r)
#pragma unroll
      for (int c = 0; c < OBB; ++c) {
        const float out = tt[r][c] / ss[r][c] * inv_c2;  // sum(z e)/sum(e)
        hout[(b0 + r) * OUT + (o0 + c)] = 1.0f - out;
      }
  }
}

extern "C" void kernel_launch(void* const* d_in, const int* in_sizes, int n_in,
                              void* d_out, int out_size, void* d_ws, size_t ws_size,
                              hipStream_t stream) {
  // setup_inputs() dict order: x, W0, tau0, W1, tau1, W2, tau2, W3, tau3
  const float* x    = (const float*)d_in[0];
  const float* W0   = (const float*)d_in[1];
  const float* tau0 = (const float*)d_in[2];
  const float* W1   = (const float*)d_in[3];
  const float* tau1 = (const float*)d_in[4];
  const float* W2   = (const float*)d_in[5];
  const float* tau2 = (const float*)d_in[6];
  const float* W3   = (const float*)d_in[7];
  const float* tau3 = (const float*)d_in[8];

  float* h1  = (float*)d_ws;        // 128*1024 floats
  float* h2  = h1 + 128 * 1024;     // 128*512
  float* h3  = h2 + 128 * 512;      // 128*256
  float* out = (float*)d_out;       // 128*128

  const double LOGR = 2.9444389791664403;  // log(0.95) - log(0.05) = log(19)
  const float tf1024 = (float)(log(1023.0) + LOGR);
  const float tf512  = (float)(log(511.0)  + LOGR);
  const float tf256  = (float)(log(255.0)  + LOGR);

  // grid = (OUT/32) * (128/BB): 512 / 256 / 256 / 256 blocks.
  or_layer<1024, 1024, 8, true ><<<512, 256, 0, stream>>>(x,  W0, tau0, h1,  tf1024);
  or_layer<1024,  512, 8, false><<<256, 256, 0, stream>>>(h1, W1, tau1, h2,  tf1024);
  or_layer< 512,  256, 4, false><<<256, 256, 0, stream>>>(h2, W2, tau2, h3,  tf512);
  or_layer< 256,  128, 2, false><<<256, 256, 0, stream>>>(h3, W3, tau3, out, tf256);
}